// Round 2
// baseline (17634.245 us; speedup 1.0000x reference)
//
#include <hip/hip_runtime.h>
#include <hip/hip_bf16.h>

typedef unsigned short u16;
typedef unsigned long long u64;
typedef __attribute__((ext_vector_type(8))) short short8v;      // MFMA bf16 frag (4 VGPR)
typedef __attribute__((ext_vector_type(8))) unsigned short ushort8v;
typedef __attribute__((ext_vector_type(4))) float float4v;

#define S_LEN 1024
#define BATCH 256
#define VOCAB 32000
#define EMBED 512
#define HIDDEN 1024

__device__ inline u16 f2bf(float f) {
  return __builtin_bit_cast(u16, __float2bfloat16(f));  // RNE
}

// ---------------- prep: W_ih -> bf16, zero hbuf + cnt ----------------
__global__ __launch_bounds__(256) void prep_kernel(const float* __restrict__ wih,
                                                   u16* __restrict__ wih16,
                                                   u16* __restrict__ hbuf,
                                                   unsigned int* __restrict__ cnt) {
  int i = blockIdx.x * 256 + threadIdx.x;
  const int NW = (HIDDEN * EMBED) / 8;      // 65536
  const int NH = (2 * BATCH * HIDDEN) / 8;  // 65536
  const int NC = S_LEN * 4;                 // 4096
  if (i < NW) {
    const float* s = wih + (size_t)i * 8;
    float4v a = *(const float4v*)s;
    float4v b = *(const float4v*)(s + 4);
    ushort8v v;
    v[0]=f2bf(a[0]); v[1]=f2bf(a[1]); v[2]=f2bf(a[2]); v[3]=f2bf(a[3]);
    v[4]=f2bf(b[0]); v[5]=f2bf(b[1]); v[6]=f2bf(b[2]); v[7]=f2bf(b[3]);
    *(ushort8v*)(wih16 + (size_t)i * 8) = v;
  } else if (i < NW + NH) {
    int j = i - NW;
    ushort8v z = {0,0,0,0,0,0,0,0};
    *(ushort8v*)(hbuf + (size_t)j * 8) = z;
  } else if (i < NW + NH + NC) {
    cnt[i - NW - NH] = 0u;
  }
}

// ---------------- embed + input projection GEMM ----------------
// C[r, h] = sum_e emb[x[r], e] * W_ih[h, e] + b_ih[h], written to d_out (= xp)
__global__ __launch_bounds__(256) void gemm_embed(const int* __restrict__ xseq,
                                                  const float* __restrict__ emb,
                                                  const u16* __restrict__ wih16,
                                                  const float* __restrict__ bih,
                                                  float* __restrict__ out) {
  __shared__ u16 At[128 * 64];   // swizzled: chunk ^= (row&7)
  __shared__ u16 Bt[128 * 64];
  __shared__ int idxc[128];
  const int tid = threadIdx.x;
  const int bid = blockIdx.x;
  const int mt = bid >> 3;       // 2048 m-tiles
  const int nt = bid & 7;        // 8 n-tiles
  if (tid < 128) idxc[tid] = xseq[mt * 128 + tid];
  const int lane = tid & 63;
  const int wid = tid >> 6;
  const int wr = wid >> 1, wc = wid & 1;
  float4v acc[4][4] = {};
  __syncthreads();
  for (int kk = 0; kk < EMBED; kk += 64) {
    #pragma unroll
    for (int s = 0; s < 4; s++) {
      int it = tid + s * 256;          // 1024 items = 128 rows x 8 chunks(16B)
      int row = it >> 3, c = it & 7;
      const float* sa = emb + (size_t)idxc[row] * EMBED + kk + c * 8;
      float4v a0 = *(const float4v*)sa;
      float4v a1 = *(const float4v*)(sa + 4);
      ushort8v va;
      va[0]=f2bf(a0[0]); va[1]=f2bf(a0[1]); va[2]=f2bf(a0[2]); va[3]=f2bf(a0[3]);
      va[4]=f2bf(a1[0]); va[5]=f2bf(a1[1]); va[6]=f2bf(a1[2]); va[7]=f2bf(a1[3]);
      *(ushort8v*)(At + row * 64 + ((c ^ (row & 7)) * 8)) = va;
      ushort8v vb = *(const ushort8v*)(wih16 + (size_t)(nt * 128 + row) * EMBED + kk + c * 8);
      *(ushort8v*)(Bt + row * 64 + ((c ^ (row & 7)) * 8)) = vb;
    }
    __syncthreads();
    #pragma unroll
    for (int ks = 0; ks < 2; ks++) {
      short8v af[4], bf[4];
      #pragma unroll
      for (int i = 0; i < 4; i++) {
        int r = wr * 64 + i * 16 + (lane & 15);
        int ca = (ks * 4 + (lane >> 4)) ^ (r & 7);
        af[i] = *(const short8v*)(At + r * 64 + ca * 8);
        int cc = wc * 64 + i * 16 + (lane & 15);
        int cb = (ks * 4 + (lane >> 4)) ^ (cc & 7);
        bf[i] = *(const short8v*)(Bt + cc * 64 + cb * 8);
      }
      #pragma unroll
      for (int i = 0; i < 4; i++)
        #pragma unroll
        for (int j = 0; j < 4; j++)
          acc[i][j] = __builtin_amdgcn_mfma_f32_16x16x32_bf16(af[i], bf[j], acc[i][j], 0, 0, 0);
    }
    __syncthreads();
  }
  #pragma unroll
  for (int j = 0; j < 4; j++) {
    int cg = nt * 128 + wc * 64 + j * 16 + (lane & 15);
    float bias = bih[cg];
    #pragma unroll
    for (int i = 0; i < 4; i++) {
      int rg = mt * 128 + wr * 64 + i * 16 + (lane >> 4) * 4;
      #pragma unroll
      for (int q = 0; q < 4; q++)
        out[(size_t)(rg + q) * HIDDEN + cg] = acc[i][j][q] + bias;
    }
  }
}

// ---------------- recurrence ----------------
// 64 blocks = 4 groups (64 batch rows) x 16 j-tiles (64 hidden cols).
// W_hh tile resident in LDS. Cross-block h exchange via RELAXED agent-scope
// atomics (per-access L2 bypass -> L3 coherent point). No acquire/release
// fences => no per-step buffer_inv / buffer_wbl2 storms.
__global__ __launch_bounds__(256) void rnn_rec(const float* __restrict__ whh,
                                               const float* __restrict__ bhh,
                                               u16* __restrict__ hbuf,
                                               float* __restrict__ out,
                                               unsigned int* __restrict__ cnt) {
  extern __shared__ u16 smem[];
  u16* Wt = smem;                    // [64][1024] bf16, chunk ^= (row&7)
  u16* hstage = smem + 64 * 1024;    // [64][64] bf16 staging for coop store
  const int tid = threadIdx.x;
  const int lane = tid & 63, wid = tid >> 6;
  const int wr = wid >> 1, wc = wid & 1;   // 2x2 waves, wave tile 32x32
  const int g = blockIdx.x & 3;
  const int jt = blockIdx.x >> 2;
  // prologue: load + convert + swizzle W_hh rows [jt*64, jt*64+64)
  for (int i = tid; i < 64 * 128; i += 256) {
    int row = i >> 7, c = i & 127;   // c = 16B chunk (8 elems)
    const float* s = whh + (size_t)(jt * 64 + row) * HIDDEN + c * 8;
    float4v a = *(const float4v*)s;
    float4v b = *(const float4v*)(s + 4);
    ushort8v v;
    v[0]=f2bf(a[0]); v[1]=f2bf(a[1]); v[2]=f2bf(a[2]); v[3]=f2bf(a[3]);
    v[4]=f2bf(b[0]); v[5]=f2bf(b[1]); v[6]=f2bf(b[2]); v[7]=f2bf(b[3]);
    *(ushort8v*)(Wt + row * 1024 + ((c ^ (row & 7)) * 8)) = v;
  }
  float bh[2];
  #pragma unroll
  for (int jj = 0; jj < 2; jj++) bh[jj] = bhh[jt * 64 + wc * 32 + jj * 16 + (lane & 15)];
  __syncthreads();

  const int rA0 = g * 64 + wr * 32 + (lane & 15);       // A rows (+i*16)
  const int cW0 = wc * 32 + (lane & 15);                // local W row (+jj*16)
  const int rO0 = g * 64 + wr * 32 + (lane >> 4) * 4;   // C rows (+i*16+q)
  const int cO0 = jt * 64 + wc * 32 + (lane & 15);      // C cols (+jj*16)
  const int lr0 = wr * 32 + (lane >> 4) * 4;            // local C row
  const int lc0 = wc * 32 + (lane & 15);                // local C col
  const int kA0 = (lane >> 4) * 8;
  // cooperative hq store mapping: thread -> 32B chunk of the 8KB tile
  const int sr = tid >> 2;              // staging row 0..63
  const int sc = (tid & 3) * 16;        // staging col (u16 units)

  for (int t = 0; t < S_LEN; t++) {
    const int p = t & 1;
    float* outt = out + (size_t)t * (BATCH * HIDDEN);
    // prefetch xp (issued before the spin; in flight during the wait)
    float xp[2][2][4];
    #pragma unroll
    for (int i = 0; i < 2; i++)
      #pragma unroll
      for (int jj = 0; jj < 2; jj++)
        #pragma unroll
        for (int q = 0; q < 4; q++)
          xp[i][jj][q] = outt[(size_t)(rO0 + i * 16 + q) * HIDDEN + cO0 + jj * 16];
    // wait for all 16 producers of h_{t-1} rows of this group (relaxed poll)
    if (t > 0) {
      if (tid == 0) {
        while (__hip_atomic_load(&cnt[(t - 1) * 4 + g], __ATOMIC_RELAXED,
                                 __HIP_MEMORY_SCOPE_AGENT) < 16u) { }
      }
      __syncthreads();
    }
    const u16* hp = hbuf + (size_t)p * (BATCH * HIDDEN);
    float4v acc[2][2] = {};
    #pragma unroll 8
    for (int k32 = 0; k32 < 32; k32++) {
      short8v a[2], b[2];
      #pragma unroll
      for (int i = 0; i < 2; i++) {
        const u64* ap = (const u64*)(hp + (size_t)(rA0 + i * 16) * HIDDEN + k32 * 32 + kA0);
        union { u64 q[2]; short8v v; } ua;
        ua.q[0] = __hip_atomic_load(ap, __ATOMIC_RELAXED, __HIP_MEMORY_SCOPE_AGENT);
        ua.q[1] = __hip_atomic_load(ap + 1, __ATOMIC_RELAXED, __HIP_MEMORY_SCOPE_AGENT);
        a[i] = ua.v;
      }
      #pragma unroll
      for (int jj = 0; jj < 2; jj++) {
        int col = cW0 + jj * 16;
        int ch = (k32 * 4 + (lane >> 4)) ^ (col & 7);
        b[jj] = *(const short8v*)(Wt + col * 1024 + ch * 8);
      }
      #pragma unroll
      for (int i = 0; i < 2; i++)
        #pragma unroll
        for (int jj = 0; jj < 2; jj++)
          acc[i][jj] = __builtin_amdgcn_mfma_f32_16x16x32_bf16(a[i], b[jj], acc[i][jj], 0, 0, 0);
    }
    // epilogue: h = tanh(acc + xp + b_hh); fp32 out (cached) + LDS stage
    #pragma unroll
    for (int i = 0; i < 2; i++)
      #pragma unroll
      for (int jj = 0; jj < 2; jj++)
        #pragma unroll
        for (int q = 0; q < 4; q++) {
          float v = acc[i][jj][q] + xp[i][jj][q] + bh[jj];
          float e = __expf(-2.0f * fabsf(v));
          float th = (1.0f - e) / (1.0f + e);
          th = copysignf(th, v);
          outt[(size_t)(rO0 + i * 16 + q) * HIDDEN + cO0 + jj * 16] = th;
          hstage[(lr0 + i * 16 + q) * 64 + lc0 + jj * 16] = f2bf(th);
        }
    __syncthreads();  // hstage complete
    // cooperative write-through store of the 8KB h tile (bypasses L2)
    {
      u16* hq = hbuf + (size_t)(p ^ 1) * (BATCH * HIDDEN);
      const u64* src = (const u64*)(hstage + sr * 64 + sc);
      u64* dst = (u64*)(hq + (size_t)(g * 64 + sr) * HIDDEN + jt * 64 + sc);
      #pragma unroll
      for (int k = 0; k < 4; k++)
        __hip_atomic_store(dst + k, src[k], __ATOMIC_RELAXED, __HIP_MEMORY_SCOPE_AGENT);
    }
    __syncthreads();  // drains vmcnt: stores retired at coherent point
    if (tid == 0)
      __hip_atomic_fetch_add(&cnt[t * 4 + g], 1u, __ATOMIC_RELAXED,
                             __HIP_MEMORY_SCOPE_AGENT);
  }
}

extern "C" void kernel_launch(void* const* d_in, const int* in_sizes, int n_in,
                              void* d_out, int out_size, void* d_ws, size_t ws_size,
                              hipStream_t stream) {
  const int* xseq   = (const int*)d_in[0];
  const float* emb  = (const float*)d_in[1];
  const float* wih  = (const float*)d_in[2];
  const float* bih  = (const float*)d_in[3];
  const float* whh  = (const float*)d_in[4];
  const float* bhh  = (const float*)d_in[5];
  float* out = (float*)d_out;
  char* ws = (char*)d_ws;
  u16* wih16 = (u16*)ws;                              // 1,048,576 B
  u16* hbuf  = (u16*)(ws + 1048576);                  // 1,048,576 B (2 x 256 x 1024 bf16)
  unsigned int* cnt = (unsigned int*)(ws + 2097152);  // 16,384 B

  prep_kernel<<<528, 256, 0, stream>>>(wih, wih16, hbuf, cnt);
  gemm_embed<<<16384, 256, 0, stream>>>(xseq, emb, wih16, bih, out);
  hipFuncSetAttribute((const void*)rnn_rec,
                      hipFuncAttributeMaxDynamicSharedMemorySize, 139264);
  rnn_rec<<<64, 256, 139264, stream>>>(whh, bhh, hbuf, out, cnt);
}

// Round 4
// 10988.350 us; speedup vs baseline: 1.6048x; 1.6048x over previous
//
#include <hip/hip_runtime.h>
#include <hip/hip_bf16.h>

typedef unsigned short u16;
typedef unsigned int u32;
typedef unsigned long long u64;
typedef __attribute__((ext_vector_type(8))) short short8v;      // MFMA bf16 frag (4 VGPR)
typedef __attribute__((ext_vector_type(8))) unsigned short ushort8v;
typedef __attribute__((ext_vector_type(4))) float float4v;

#define S_LEN 1024
#define BATCH 256
#define VOCAB 32000
#define EMBED 512
#define HIDDEN 1024

__device__ inline u16 f2bf(float f) {
  return __builtin_bit_cast(u16, __float2bfloat16(f));  // RNE
}

// ---------------- prep: W_ih -> bf16, zero hbuf + flags ----------------
__global__ __launch_bounds__(256) void prep_kernel(const float* __restrict__ wih,
                                                   u16* __restrict__ wih16,
                                                   u16* __restrict__ hbuf,
                                                   u32* __restrict__ flag) {
  int i = blockIdx.x * 256 + threadIdx.x;
  const int NW = (HIDDEN * EMBED) / 8;      // 65536
  const int NH = (2 * BATCH * HIDDEN) / 8;  // 65536
  if (i < NW) {
    const float* s = wih + (size_t)i * 8;
    float4v a = *(const float4v*)s;
    float4v b = *(const float4v*)(s + 4);
    ushort8v v;
    v[0]=f2bf(a[0]); v[1]=f2bf(a[1]); v[2]=f2bf(a[2]); v[3]=f2bf(a[3]);
    v[4]=f2bf(b[0]); v[5]=f2bf(b[1]); v[6]=f2bf(b[2]); v[7]=f2bf(b[3]);
    *(ushort8v*)(wih16 + (size_t)i * 8) = v;
  } else if (i < NW + NH) {
    int j = i - NW;
    ushort8v z = {0,0,0,0,0,0,0,0};
    *(ushort8v*)(hbuf + (size_t)j * 8) = z;
  } else if (i < NW + NH + 64) {
    flag[i - NW - NH] = 0u;
  }
}

// ---------------- embed + input projection GEMM ----------------
__global__ __launch_bounds__(256) void gemm_embed(const int* __restrict__ xseq,
                                                  const float* __restrict__ emb,
                                                  const u16* __restrict__ wih16,
                                                  const float* __restrict__ bih,
                                                  float* __restrict__ out) {
  __shared__ u16 At[128 * 64];   // swizzled: chunk ^= (row&7)
  __shared__ u16 Bt[128 * 64];
  __shared__ int idxc[128];
  const int tid = threadIdx.x;
  const int bid = blockIdx.x;
  const int mt = bid >> 3;       // 2048 m-tiles
  const int nt = bid & 7;        // 8 n-tiles
  if (tid < 128) idxc[tid] = xseq[mt * 128 + tid];
  const int lane = tid & 63;
  const int wid = tid >> 6;
  const int wr = wid >> 1, wc = wid & 1;
  float4v acc[4][4] = {};
  __syncthreads();
  for (int kk = 0; kk < EMBED; kk += 64) {
    #pragma unroll
    for (int s = 0; s < 4; s++) {
      int it = tid + s * 256;          // 1024 items = 128 rows x 8 chunks(16B)
      int row = it >> 3, c = it & 7;
      const float* sa = emb + (size_t)idxc[row] * EMBED + kk + c * 8;
      float4v a0 = *(const float4v*)sa;
      float4v a1 = *(const float4v*)(sa + 4);
      ushort8v va;
      va[0]=f2bf(a0[0]); va[1]=f2bf(a0[1]); va[2]=f2bf(a0[2]); va[3]=f2bf(a0[3]);
      va[4]=f2bf(a1[0]); va[5]=f2bf(a1[1]); va[6]=f2bf(a1[2]); va[7]=f2bf(a1[3]);
      *(ushort8v*)(At + row * 64 + ((c ^ (row & 7)) * 8)) = va;
      ushort8v vb = *(const ushort8v*)(wih16 + (size_t)(nt * 128 + row) * EMBED + kk + c * 8);
      *(ushort8v*)(Bt + row * 64 + ((c ^ (row & 7)) * 8)) = vb;
    }
    __syncthreads();
    #pragma unroll
    for (int ks = 0; ks < 2; ks++) {
      short8v af[4], bf[4];
      #pragma unroll
      for (int i = 0; i < 4; i++) {
        int r = wr * 64 + i * 16 + (lane & 15);
        int ca = (ks * 4 + (lane >> 4)) ^ (r & 7);
        af[i] = *(const short8v*)(At + r * 64 + ca * 8);
        int cc = wc * 64 + i * 16 + (lane & 15);
        int cb = (ks * 4 + (lane >> 4)) ^ (cc & 7);
        bf[i] = *(const short8v*)(Bt + cc * 64 + cb * 8);
      }
      #pragma unroll
      for (int i = 0; i < 4; i++)
        #pragma unroll
        for (int j = 0; j < 4; j++)
          acc[i][j] = __builtin_amdgcn_mfma_f32_16x16x32_bf16(af[i], bf[j], acc[i][j], 0, 0, 0);
    }
    __syncthreads();
  }
  #pragma unroll
  for (int j = 0; j < 4; j++) {
    int cg = nt * 128 + wc * 64 + j * 16 + (lane & 15);
    float bias = bih[cg];
    #pragma unroll
    for (int i = 0; i < 4; i++) {
      int rg = mt * 128 + wr * 64 + i * 16 + (lane >> 4) * 4;
      #pragma unroll
      for (int q = 0; q < 4; q++)
        out[(size_t)(rg + q) * HIDDEN + cg] = acc[i][j][q] + bias;
    }
  }
}

// ---------------- recurrence ----------------
// 64 blocks = 4 groups (64 batch rows) x 16 j-tiles (64 hidden cols).
// W_hh tile resident in LDS. Producer: LDS-stage + relaxed SYSTEM u64 atomic
// stores (write-through) + vmcnt drain + flag. Consumer: relaxed flag poll,
// ONE agent acquire-fence (buffer_inv) per step, then PLAIN cached pipelined
// loads of h (compiler-scheduled, m97-style).
__global__ __launch_bounds__(256) void rnn_rec(const float* __restrict__ whh,
                                               const float* __restrict__ bhh,
                                               u16* __restrict__ hbuf,
                                               float* __restrict__ out,
                                               u32* __restrict__ flag) {
  extern __shared__ u16 smem[];
  u16* Wt = smem;                    // [64][1024] bf16, chunk ^= (row&7)
  u16* hstage = smem + 64 * 1024;    // [64][64] bf16 staging for coop store
  const int tid = threadIdx.x;
  const int lane = tid & 63, w = tid >> 6;   // 4 waves, wave tile 16 rows x 64 cols
  const int g = blockIdx.x & 3;
  const int jt = blockIdx.x >> 2;
  // prologue: load + convert + swizzle W_hh rows [jt*64, jt*64+64)
  for (int i = tid; i < 64 * 128; i += 256) {
    int row = i >> 7, c = i & 127;   // c = 16B chunk (8 elems)
    const float* s = whh + (size_t)(jt * 64 + row) * HIDDEN + c * 8;
    float4v a = *(const float4v*)s;
    float4v b = *(const float4v*)(s + 4);
    ushort8v v;
    v[0]=f2bf(a[0]); v[1]=f2bf(a[1]); v[2]=f2bf(a[2]); v[3]=f2bf(a[3]);
    v[4]=f2bf(b[0]); v[5]=f2bf(b[1]); v[6]=f2bf(b[2]); v[7]=f2bf(b[3]);
    *(ushort8v*)(Wt + row * 1024 + ((c ^ (row & 7)) * 8)) = v;
  }
  const int l15 = lane & 15, l4 = lane >> 4;
  float bh[4];
  #pragma unroll
  for (int jj = 0; jj < 4; jj++) bh[jj] = bhh[jt * 64 + jj * 16 + l15];
  __syncthreads();

  const int rA  = g * 64 + w * 16 + l15;      // A-frag row (global batch row)
  const int rO0 = g * 64 + w * 16 + l4 * 4;   // C rows (+q)
  const int cO0 = jt * 64 + l15;              // C cols (+jj*16)
  const int lr0 = w * 16 + l4 * 4;            // local C row in hstage
  // cooperative hbuf store mapping: thread -> 32B chunk of the 8KB tile
  const int sr = tid >> 2;                    // staging row 0..63
  const int sc = (tid & 3) * 16;              // staging col (u16 units)

  for (int t = 0; t < S_LEN; t++) {
    const int p = t & 1;
    float* outt = out + (size_t)t * (BATCH * HIDDEN);
    // xp prefetch (in flight during the poll)
    float xp[4][4];
    #pragma unroll
    for (int jj = 0; jj < 4; jj++)
      #pragma unroll
      for (int q = 0; q < 4; q++)
        xp[jj][q] = outt[(size_t)(rO0 + q) * HIDDEN + cO0 + jj * 16];
    // wait for the 16 producers of h_{t-1} in this group (parallel poll)
    if (t > 0) {
      if (tid < 16) {
        u32* f = flag + g * 16 + tid;
        while (__hip_atomic_load(f, __ATOMIC_RELAXED, __HIP_MEMORY_SCOPE_SYSTEM) < (u32)t) { }
      }
      __syncthreads();
      // one L2-invalidate per step; h loads below are plain cached loads
      __builtin_amdgcn_fence(__ATOMIC_ACQUIRE, "agent");
    }
    const u16* __restrict__ hp = hbuf + (size_t)p * (BATCH * HIDDEN);
    const u16* __restrict__ pa = hp + (size_t)rA * HIDDEN + l4 * 8;
    float4v acc[4] = {};
    #pragma unroll
    for (int k32 = 0; k32 < 32; k32++) {
      short8v a = *(const short8v*)(pa + k32 * 32);
      #pragma unroll
      for (int jj = 0; jj < 4; jj++) {
        int col = jj * 16 + l15;
        int ch = (k32 * 4 + l4) ^ (col & 7);
        short8v b = *(const short8v*)(Wt + col * 1024 + ch * 8);
        acc[jj] = __builtin_amdgcn_mfma_f32_16x16x32_bf16(a, b, acc[jj], 0, 0, 0);
      }
    }
    // epilogue: h = tanh(acc + xp + b_hh); fp32 out (cached) + LDS stage
    #pragma unroll
    for (int jj = 0; jj < 4; jj++)
      #pragma unroll
      for (int q = 0; q < 4; q++) {
        float v = acc[jj][q] + xp[jj][q] + bh[jj];
        float e = __expf(-2.0f * fabsf(v));
        float th = (1.0f - e) / (1.0f + e);
        th = copysignf(th, v);
        outt[(size_t)(rO0 + q) * HIDDEN + cO0 + jj * 16] = th;
        hstage[(lr0 + q) * 64 + jj * 16 + l15] = f2bf(th);
      }
    __syncthreads();  // hstage complete
    // cooperative write-through store of the 8KB h tile (relaxed system u64)
    {
      u16* hq = hbuf + (size_t)(p ^ 1) * (BATCH * HIDDEN);
      const u64* src = (const u64*)(hstage + sr * 64 + sc);
      u64* dst = (u64*)(hq + (size_t)(g * 64 + sr) * HIDDEN + jt * 64 + sc);
      #pragma unroll
      for (int k = 0; k < 4; k++)
        __hip_atomic_store(dst + k, src[k], __ATOMIC_RELAXED, __HIP_MEMORY_SCOPE_SYSTEM);
    }
    asm volatile("s_waitcnt vmcnt(0)" ::: "memory");  // this wave's stores at L3
    __syncthreads();                                  // all waves drained
    if (tid == 0)
      __hip_atomic_store(&flag[g * 16 + jt], (u32)(t + 1), __ATOMIC_RELAXED,
                         __HIP_MEMORY_SCOPE_SYSTEM);
  }
}

extern "C" void kernel_launch(void* const* d_in, const int* in_sizes, int n_in,
                              void* d_out, int out_size, void* d_ws, size_t ws_size,
                              hipStream_t stream) {
  const int* xseq   = (const int*)d_in[0];
  const float* emb  = (const float*)d_in[1];
  const float* wih  = (const float*)d_in[2];
  const float* bih  = (const float*)d_in[3];
  const float* whh  = (const float*)d_in[4];
  const float* bhh  = (const float*)d_in[5];
  float* out = (float*)d_out;
  char* ws = (char*)d_ws;
  u16* wih16 = (u16*)ws;                      // 1,048,576 B
  u16* hbuf  = (u16*)(ws + 1048576);          // 1,048,576 B (2 x 256 x 1024 bf16)
  u32* flag  = (u32*)(ws + 2097152);          // 256 B (64 value-based flags)

  prep_kernel<<<528, 256, 0, stream>>>(wih, wih16, hbuf, flag);
  gemm_embed<<<16384, 256, 0, stream>>>(xseq, emb, wih16, bih, out);
  hipFuncSetAttribute((const void*)rnn_rec,
                      hipFuncAttributeMaxDynamicSharedMemorySize, 139264);
  rnn_rec<<<64, 256, 139264, stream>>>(whh, bhh, hbuf, out, flag);
}